// Round 2
// baseline (151.191 us; speedup 1.0000x reference)
//
#include <hip/hip_runtime.h>

#define N_FEAT 2048
#define ORDER 8
#define BATCH 8192
#define BLOCK 256

__device__ __forceinline__ float dot4(float4 a, float4 b) {
    return a.x * b.x + a.y * b.y + a.z * b.z + a.w * b.w;
}

// Kernel 1a: normalize each of the 8 reflection vectors (row-wise L2) into ws.
__global__ __launch_bounds__(BLOCK) void normalize_v_kernel(
    const float* __restrict__ v, float* __restrict__ vn) {
    const int row = blockIdx.x;          // 0..ORDER-1
    const int tid = threadIdx.x;
    const float* vr = v + (size_t)row * N_FEAT;

    float ss = 0.f;
    #pragma unroll
    for (int k = tid; k < N_FEAT; k += BLOCK) {
        float a = vr[k];
        ss += a * a;
    }
    #pragma unroll
    for (int o = 32; o > 0; o >>= 1) ss += __shfl_down(ss, o, 64);
    __shared__ float red[4];
    const int lane = tid & 63, wid = tid >> 6;
    if (lane == 0) red[wid] = ss;
    __syncthreads();
    const float inv = 1.0f / sqrtf(red[0] + red[1] + red[2] + red[3]);
    #pragma unroll
    for (int k = tid; k < N_FEAT; k += BLOCK) {
        vn[(size_t)row * N_FEAT + k] = vr[k] * inv;
    }
}

// Kernel 1b (1 block): Gram matrix G = Vn Vn^T (8x8), then build the compact-WY
// T factor: H0 H1 ... H7 = I - V T V^T, T upper-tri, diag 2,
// T[j][k] = -2 * sum_{m=j}^{k-1} T[j][m] * G[m][k].
__global__ __launch_bounds__(BLOCK) void gram_t_kernel(
    const float* __restrict__ vn, float* __restrict__ Tout) {
    const int tid = threadIdx.x;
    const int lane = tid & 63, wid = tid >> 6;

    float4 a0[ORDER], a1[ORDER];
    #pragma unroll
    for (int i = 0; i < ORDER; ++i) {
        a0[i] = *(const float4*)(vn + (size_t)i * N_FEAT + tid * 4);
        a1[i] = *(const float4*)(vn + (size_t)i * N_FEAT + 1024 + tid * 4);
    }
    // 28 upper-triangle pair dots (diag == 1 after normalization)
    float acc[28];
    #pragma unroll
    for (int i = 0, c = 0; i < ORDER; ++i)
        #pragma unroll
        for (int j = i + 1; j < ORDER; ++j, ++c)
            acc[c] = dot4(a0[i], a0[j]) + dot4(a1[i], a1[j]);
    #pragma unroll
    for (int o = 32; o > 0; o >>= 1)
        #pragma unroll
        for (int c = 0; c < 28; ++c) acc[c] += __shfl_down(acc[c], o, 64);

    __shared__ float gred[4][28];
    if (lane == 0) {
        #pragma unroll
        for (int c = 0; c < 28; ++c) gred[wid][c] = acc[c];
    }
    __syncthreads();
    if (tid == 0) {
        float G[ORDER][ORDER];
        for (int i = 0, c = 0; i < ORDER; ++i) {
            G[i][i] = 1.0f;
            for (int j = i + 1; j < ORDER; ++j, ++c) {
                float g = gred[0][c] + gred[1][c] + gred[2][c] + gred[3][c];
                G[i][j] = g; G[j][i] = g;
            }
        }
        float T[ORDER][ORDER];
        for (int i = 0; i < ORDER; ++i)
            for (int j = 0; j < ORDER; ++j) T[i][j] = 0.f;
        T[0][0] = 2.0f;
        for (int k = 1; k < ORDER; ++k) {
            for (int j = 0; j < k; ++j) {
                float s = 0.f;
                for (int m = j; m < k; ++m) s += T[j][m] * G[m][k];
                T[j][k] = -2.0f * s;
            }
            T[k][k] = 2.0f;
        }
        for (int i = 0; i < ORDER; ++i)
            for (int j = 0; j < ORDER; ++j) Tout[i * ORDER + j] = T[i][j];
    }
}

// Kernel 2: one block per batch row.
// z' = z - (z V) T V^T ; y = z' * d + bias.  ONE barrier per block.
__global__ __launch_bounds__(BLOCK) void orth_apply_kernel(
    const float* __restrict__ x, const float* __restrict__ vn,
    const float* __restrict__ T, const float* __restrict__ d,
    const float* __restrict__ bias, float* __restrict__ y) {
    const int row = blockIdx.x;
    const int tid = threadIdx.x;
    const int lane = tid & 63, wid = tid >> 6;
    const size_t base = (size_t)row * N_FEAT;

    float4 z0 = *(const float4*)(x + base + tid * 4);
    float4 z1 = *(const float4*)(x + base + 1024 + tid * 4);

    // Hold all 8 reflection-vector fragments in registers (used twice).
    float4 a0[ORDER], a1[ORDER];
    #pragma unroll
    for (int i = 0; i < ORDER; ++i) {
        a0[i] = *(const float4*)(vn + (size_t)i * N_FEAT + tid * 4);
        a1[i] = *(const float4*)(vn + (size_t)i * N_FEAT + 1024 + tid * 4);
    }

    // p_i = z . v_i  (8 independent partial dots -> one reduction round)
    float p[ORDER];
    #pragma unroll
    for (int i = 0; i < ORDER; ++i)
        p[i] = dot4(z0, a0[i]) + dot4(z1, a1[i]);
    #pragma unroll
    for (int o = 32; o > 0; o >>= 1)
        #pragma unroll
        for (int i = 0; i < ORDER; ++i) p[i] += __shfl_down(p[i], o, 64);

    __shared__ float red[4][ORDER];
    __shared__ float tlds[ORDER * ORDER];
    if (tid < ORDER * ORDER) tlds[tid] = T[tid];
    if (lane == 0) {
        #pragma unroll
        for (int i = 0; i < ORDER; ++i) red[wid][i] = p[i];
    }
    __syncthreads();   // the ONLY barrier

    float pp[ORDER];
    #pragma unroll
    for (int i = 0; i < ORDER; ++i)
        pp[i] = red[0][i] + red[1][i] + red[2][i] + red[3][i];

    // q = -(p T)  (T upper-triangular)
    float q[ORDER];
    #pragma unroll
    for (int j = 0; j < ORDER; ++j) {
        float s = 0.f;
        #pragma unroll
        for (int i = 0; i <= j; ++i) s += pp[i] * tlds[i * ORDER + j];
        q[j] = -s;
    }

    // z' = z + sum_j q_j * v_j
    #pragma unroll
    for (int j = 0; j < ORDER; ++j) {
        z0.x += q[j] * a0[j].x; z0.y += q[j] * a0[j].y;
        z0.z += q[j] * a0[j].z; z0.w += q[j] * a0[j].w;
        z1.x += q[j] * a1[j].x; z1.y += q[j] * a1[j].y;
        z1.z += q[j] * a1[j].z; z1.w += q[j] * a1[j].w;
    }

    const float4 d0 = *(const float4*)(d + tid * 4);
    const float4 d1 = *(const float4*)(d + 1024 + tid * 4);
    const float4 b0 = *(const float4*)(bias + tid * 4);
    const float4 b1 = *(const float4*)(bias + 1024 + tid * 4);

    float4 o0, o1;
    o0.x = z0.x * d0.x + b0.x; o0.y = z0.y * d0.y + b0.y;
    o0.z = z0.z * d0.z + b0.z; o0.w = z0.w * d0.w + b0.w;
    o1.x = z1.x * d1.x + b1.x; o1.y = z1.y * d1.y + b1.y;
    o1.z = z1.z * d1.z + b1.z; o1.w = z1.w * d1.w + b1.w;

    *(float4*)(y + base + tid * 4) = o0;
    *(float4*)(y + base + 1024 + tid * 4) = o1;
}

extern "C" void kernel_launch(void* const* d_in, const int* in_sizes, int n_in,
                              void* d_out, int out_size, void* d_ws, size_t ws_size,
                              hipStream_t stream) {
    const float* x    = (const float*)d_in[0];  // [8192, 2048]
    const float* v    = (const float*)d_in[1];  // [8, 2048]
    const float* d    = (const float*)d_in[2];  // [2048]
    const float* bias = (const float*)d_in[3];  // [2048]
    float* y  = (float*)d_out;                  // [8192, 2048]
    float* vn = (float*)d_ws;                   // [8, 2048]
    float* T  = vn + ORDER * N_FEAT;            // [8, 8]

    normalize_v_kernel<<<ORDER, BLOCK, 0, stream>>>(v, vn);
    gram_t_kernel<<<1, BLOCK, 0, stream>>>(vn, T);
    orth_apply_kernel<<<BATCH, BLOCK, 0, stream>>>(x, vn, T, d, bias, y);
}

// Round 4
// 126.085 us; speedup vs baseline: 1.1991x; 1.1991x over previous
//
#include <hip/hip_runtime.h>

#define N_FEAT 2048
#define ORDER 8
#define BATCH 8192
#define BLOCK 256
#define ROWS 4          // batch rows per block

typedef float v4f __attribute__((ext_vector_type(4)));

__device__ __forceinline__ float dot4(v4f a, v4f b) {
    return a.x * b.x + a.y * b.y + a.z * b.z + a.w * b.w;
}

// Prep kernel (1 block): normalize the 8 reflection vectors into ws.
__global__ __launch_bounds__(BLOCK) void prep_kernel(
    const float* __restrict__ v, float* __restrict__ vn) {
    const int tid = threadIdx.x;
    const int lane = tid & 63, wid = tid >> 6;

    v4f a0[ORDER], a1[ORDER];
    #pragma unroll
    for (int i = 0; i < ORDER; ++i) {
        a0[i] = *(const v4f*)(v + (size_t)i * N_FEAT + tid * 4);
        a1[i] = *(const v4f*)(v + (size_t)i * N_FEAT + 1024 + tid * 4);
    }
    float ss[ORDER];
    #pragma unroll
    for (int i = 0; i < ORDER; ++i)
        ss[i] = dot4(a0[i], a0[i]) + dot4(a1[i], a1[i]);
    #pragma unroll
    for (int o = 32; o > 0; o >>= 1)
        #pragma unroll
        for (int i = 0; i < ORDER; ++i) ss[i] += __shfl_down(ss[i], o, 64);

    __shared__ float red[4][ORDER];
    if (lane == 0) {
        #pragma unroll
        for (int i = 0; i < ORDER; ++i) red[wid][i] = ss[i];
    }
    __syncthreads();
    #pragma unroll
    for (int i = 0; i < ORDER; ++i) {
        const float inv = 1.0f / sqrtf(red[0][i] + red[1][i] + red[2][i] + red[3][i]);
        *(v4f*)(vn + (size_t)i * N_FEAT + tid * 4) = a0[i] * inv;
        *(v4f*)(vn + (size_t)i * N_FEAT + 1024 + tid * 4) = a1[i] * inv;
    }
}

// Apply kernel: ROWS batch rows per block. Serialized reflections (8 iters),
// each iteration amortizes one vn-fragment load over ROWS independent rows.
// Double-buffered LDS reduction -> ONE barrier per iteration.
__global__ __launch_bounds__(BLOCK) void orth_apply_kernel(
    const float* __restrict__ x, const float* __restrict__ vn,
    const float* __restrict__ d, const float* __restrict__ bias,
    float* __restrict__ y) {
    const int tid = threadIdx.x;
    const int lane = tid & 63, wid = tid >> 6;
    const size_t base = (size_t)blockIdx.x * ROWS * N_FEAT;
    const int c0 = tid * 4;          // columns [c0, c0+3]
    const int c1 = 1024 + tid * 4;   // columns [c1, c1+3]

    // Load ROWS rows of x: 2*ROWS independent 16B loads in flight.
    v4f z0[ROWS], z1[ROWS];
    #pragma unroll
    for (int r = 0; r < ROWS; ++r) {
        z0[r] = *(const v4f*)(x + base + (size_t)r * N_FEAT + c0);
        z1[r] = *(const v4f*)(x + base + (size_t)r * N_FEAT + c1);
    }

    __shared__ float red[2][4][ROWS];

    #pragma unroll
    for (int i = 0; i < ORDER; ++i) {
        const float* vr = vn + (size_t)i * N_FEAT;
        const v4f a0 = *(const v4f*)(vr + c0);
        const v4f a1 = *(const v4f*)(vr + c1);

        float p[ROWS];
        #pragma unroll
        for (int r = 0; r < ROWS; ++r)
            p[r] = dot4(z0[r], a0) + dot4(z1[r], a1);
        #pragma unroll
        for (int o = 32; o > 0; o >>= 1)
            #pragma unroll
            for (int r = 0; r < ROWS; ++r) p[r] += __shfl_down(p[r], o, 64);

        const int buf = i & 1;
        if (lane == 0) {
            #pragma unroll
            for (int r = 0; r < ROWS; ++r) red[buf][wid][r] = p[r];
        }
        __syncthreads();   // one barrier/iter; buffers alternate so no 2nd sync

        #pragma unroll
        for (int r = 0; r < ROWS; ++r) {
            const float s = -2.0f * (red[buf][0][r] + red[buf][1][r] +
                                     red[buf][2][r] + red[buf][3][r]);
            z0[r] += s * a0;
            z1[r] += s * a1;
        }
    }

    const v4f d0 = *(const v4f*)(d + c0);
    const v4f d1 = *(const v4f*)(d + c1);
    const v4f b0 = *(const v4f*)(bias + c0);
    const v4f b1 = *(const v4f*)(bias + c1);

    #pragma unroll
    for (int r = 0; r < ROWS; ++r) {
        v4f o0 = z0[r] * d0 + b0;
        v4f o1 = z1[r] * d1 + b1;
        __builtin_nontemporal_store(o0, (v4f*)(y + base + (size_t)r * N_FEAT + c0));
        __builtin_nontemporal_store(o1, (v4f*)(y + base + (size_t)r * N_FEAT + c1));
    }
}

extern "C" void kernel_launch(void* const* d_in, const int* in_sizes, int n_in,
                              void* d_out, int out_size, void* d_ws, size_t ws_size,
                              hipStream_t stream) {
    const float* x    = (const float*)d_in[0];  // [8192, 2048]
    const float* v    = (const float*)d_in[1];  // [8, 2048]
    const float* d    = (const float*)d_in[2];  // [2048]
    const float* bias = (const float*)d_in[3];  // [2048]
    float* y  = (float*)d_out;                  // [8192, 2048]
    float* vn = (float*)d_ws;                   // [8, 2048]

    prep_kernel<<<1, BLOCK, 0, stream>>>(v, vn);
    orth_apply_kernel<<<BATCH / ROWS, BLOCK, 0, stream>>>(x, vn, d, bias, y);
}